// Round 18
// baseline (660.843 us; speedup 1.0000x reference)
//
#include <hip/hip_runtime.h>
#include <cstdint>
#include <cstddef>

typedef __bf16 bf16_t;
typedef float f32x4 __attribute__((ext_vector_type(4)));
typedef __bf16 bf16x8 __attribute__((ext_vector_type(8)));

// ---------------- problem constants ----------------
#define TOKENS      16384
#define IN_F        4096
#define OUT_F       4096
#define NACT        2048
#define MHALF       8192

// ---------------- workspace layout (bytes) ----------------
static constexpr size_t OFF_PERM  = 0;                      // 4096 * 4
static constexpr size_t OFF_ACT   = 16384;                  // 2048 * 4
static constexpr size_t OFF_OIP   = 24576;                  // 4096 * 4
static constexpr size_t OFF_OP    = 40960;                  // 4096 * 4
static constexpr size_t OFF_IPINV = 57344;                  // 4096 * 4
static constexpr size_t OFF_DHT   = 73728;                  // 128*128 * 2 (bf16)
static constexpr size_t OFF_TAB   = 106496;                 // 16384 * 4 cos table
static constexpr size_t OFF_T     = 172032;                 // 8 MB
static constexpr size_t OFF_AM    = OFF_T    + 8388608;     // 32 MB
static constexpr size_t OFF_WOUT  = OFF_AM   + 33554432;    // 16 MB
static constexpr size_t WS_SMALL  = OFF_WOUT + 16777216;    // ~59 MB
// xa-half (32 MB) overlays dead T+Amat region during main phase
static constexpr size_t OFF_XA_S  = OFF_T;

// ---------------- helpers ----------------
__device__ __forceinline__ void gload_lds16(const void* gsrc, void* ldsdst) {
    __builtin_amdgcn_global_load_lds(
        (__attribute__((address_space(1))) void*)(uintptr_t)gsrc,
        (__attribute__((address_space(3))) void*)(uint32_t)(uintptr_t)ldsdst,
        16, 0, 0);
}

__device__ __forceinline__ int is_i64_flag(const int* p) {
    int s = 0;
    #pragma unroll
    for (int i = 1; i < 64; i += 2) s |= p[i];
    return s == 0;
}

// ---------------- index normalization (int64-or-int32 -> int32) ----------------
__global__ void k_norm_idx(const int* __restrict__ perm_raw,
                           const int* __restrict__ act_raw,
                           const int* __restrict__ oip_raw,
                           int* __restrict__ perm, int* __restrict__ act,
                           int* __restrict__ oip) {
    int i = blockIdx.x * blockDim.x + threadIdx.x;
    int p64 = is_i64_flag(perm_raw);
    int a64 = is_i64_flag(act_raw);
    int o64 = is_i64_flag(oip_raw);
    if (i < 4096) perm[i] = p64 ? perm_raw[2*i] : perm_raw[i];
    if (i < 2048) act[i]  = a64 ? act_raw[2*i]  : act_raw[i];
    if (i < 4096) oip[i]  = o64 ? oip_raw[2*i]  : oip_raw[i];
}

__global__ void k_invert(const int* __restrict__ oip, const int* __restrict__ perm,
                         int* __restrict__ op, int* __restrict__ ipinv) {
    int j = blockIdx.x * 256 + threadIdx.x;
    if (j < 4096) {
        op[oip[j]]     = j;   // forward output perm
        ipinv[perm[j]] = j;   // inverse input perm
    }
}

// ---------------- cos table: tab[i] = cos(pi * i / 8192), i in [0,16384) ----------------
// sin(pi*t/8192) = cos(pi*t/8192 + 3pi/2) = tab[(t + 12288) & 16383]
__global__ void k_costab(float* __restrict__ tab) {
    int i = blockIdx.x * 256 + threadIdx.x;    // 64 blocks
    tab[i] = cosf((float)i * 3.834951969e-4f);
}

// ---------------- DCT-128 transpose table, bf16: DhT[m][k] = Dh[k][m] ----------------
__global__ void k_dht(const float* __restrict__ tab, bf16_t* __restrict__ DhT) {
    int idx = blockIdx.x * 256 + threadIdx.x;   // 64 blocks
    int m = idx >> 7, k = idx & 127;
    unsigned ph = ((unsigned)(2*m + 1) * (unsigned)k) & 511u;   // period 4n = 512
    float v = 0.125f * tab[ph << 5];                            // cos(pi*ph/256)
    if (k == 0) v *= 0.70710678119f;
    DhT[m*128 + k] = (bf16_t)v;
}

// ---------------- T[r,j,q,k,u] = sum_s G2[r,j,q,s] * G3[s,k,u] ----------------
__global__ __launch_bounds__(256) void k_build_T(const float* __restrict__ G2,
                                                 const float* __restrict__ G3,
                                                 float* __restrict__ T) {
    __shared__ alignas(16) float g3s[64*8*16];   // 32 KB
    __shared__ float g2t[64*16];                 // [s][q], 4 KB
    int rj = blockIdx.x;                          // 1024 blocks: r*16 + j
    int r = rj >> 4, j = rj & 15;
    for (int idx = threadIdx.x; idx < 8192; idx += 256) g3s[idx] = G3[idx];
    for (int idx = threadIdx.x; idx < 1024; idx += 256) {
        int s = idx >> 4, q = idx & 15;
        g2t[idx] = G2[((size_t)((r*16 + j)*16 + q))*64 + s];
    }
    __syncthreads();
    int q = threadIdx.x >> 4, u = threadIdx.x & 15;
    float acc[8] = {0.f};
    for (int s = 0; s < 64; ++s) {
        float g2 = g2t[s*16 + q];
        #pragma unroll
        for (int k = 0; k < 8; ++k) acc[k] += g2 * g3s[(s*8 + k)*16 + u];
    }
    size_t base = ((size_t)((r*16 + j)*16 + q) * 8) * 16 + u;
    #pragma unroll
    for (int k = 0; k < 8; ++k) T[base + k*16] = acc[k];
}

// ---------------- A[cin][cout] = sum_r G1[i,p,r] * T[r,j,q,k,u] ----------------
__global__ __launch_bounds__(256) void k_build_A(const float* __restrict__ G1,
                                                 const float* __restrict__ T,
                                                 float* __restrict__ Amat) {
    __shared__ alignas(16) float Tl[64*16*16];   // [r][q][slot-swizzled], 64 KB
    __shared__ float g1t[64*16];                 // [r][p], 4 KB
    int cin = blockIdx.x;                         // 2048 blocks
    int i = cin >> 7, j = (cin >> 3) & 15, k = cin & 7;
    #pragma unroll
    for (int it = 0; it < 16; ++it) {
        int idx = it*256 + threadIdx.x;          // f32x4 index, 0..4095
        int slot = idx & 3, q = (idx >> 2) & 15, r = idx >> 6;
        f32x4 tv = *(const f32x4*)&T[(((((size_t)r*16 + j)*16 + q)*8) + k)*16 + slot*4];
        *(f32x4*)&Tl[(r*16 + q)*16 + ((slot ^ ((q >> 1) & 3)) << 2)] = tv;
    }
    for (int idx = threadIdx.x; idx < 1024; idx += 256) {
        int r = idx >> 4, p = idx & 15;
        g1t[idx] = G1[(i*16 + p)*64 + r];
    }
    __syncthreads();
    int p = threadIdx.x >> 4, q = threadIdx.x & 15;
    int qs = (q >> 1) & 3;
    f32x4 acc4[4];
    #pragma unroll
    for (int a = 0; a < 4; ++a) acc4[a] = (f32x4){0.f, 0.f, 0.f, 0.f};
    for (int r = 0; r < 64; ++r) {
        float g = g1t[r*16 + p];
        #pragma unroll
        for (int ub = 0; ub < 4; ++ub) {         // static acc index, runtime address
            f32x4 tv = *(const f32x4*)&Tl[(r*16 + q)*16 + ((ub ^ qs) << 2)];
            acc4[ub] += tv * g;
        }
    }
    size_t base = (size_t)cin * 4096 + p*256 + q*16;
    #pragma unroll
    for (int ub = 0; ub < 4; ++ub) *(f32x4*)&Amat[base + ub*4] = acc4[ub];
}

// ---- WoutT via MFMA: Out[128c][128m] = A_blk[c][k](bf16) x DhT[m][k](bf16)^T ----
__global__ __launch_bounds__(256) void k_wout_mfma(const float* __restrict__ Amat,
                                                   const bf16_t* __restrict__ DhT,
                                                   const int* __restrict__ op,
                                                   bf16_t* __restrict__ WoutT) {
    __shared__ alignas(16) bf16_t Al[128*128];   // 32 KB  [c][k]
    __shared__ alignas(16) bf16_t Bl[128*128];   // 32 KB  [m][k]
    const int h  = blockIdx.x;
    const int c0 = blockIdx.y * 128;
    const int t = threadIdx.x, lane = t & 63, wv = t >> 6;
    const int wm = wv >> 1, wn = wv & 1;
    const int frow = lane & 15, kg = lane >> 4;

    #pragma unroll
    for (int it = 0; it < 8; ++it) {
        int idx = it*256 + t;                    // 0..2047
        int row = idx >> 4, slot = idx & 15;
        int dst = row*256 + ((slot*16) ^ ((row & 7) << 4));   // byte offset
        const float* s = Amat + (size_t)(c0 + row)*4096 + h*128 + slot*8;
        f32x4 v0 = *(const f32x4*)s;
        f32x4 v1 = *(const f32x4*)(s + 4);
        bf16x8 av;
        av[0]=(bf16_t)v0[0]; av[1]=(bf16_t)v0[1]; av[2]=(bf16_t)v0[2]; av[3]=(bf16_t)v0[3];
        av[4]=(bf16_t)v1[0]; av[5]=(bf16_t)v1[1]; av[6]=(bf16_t)v1[2]; av[7]=(bf16_t)v1[3];
        *(bf16x8*)((char*)Al + dst) = av;
        bf16x8 dv = *(const bf16x8*)(DhT + row*128 + slot*8);
        *(bf16x8*)((char*)Bl + dst) = dv;
    }
    __syncthreads();

    f32x4 acc[4][4];
    #pragma unroll
    for (int a = 0; a < 4; ++a)
        #pragma unroll
        for (int b = 0; b < 4; ++b) acc[a][b] = (f32x4){0.f, 0.f, 0.f, 0.f};

    #pragma unroll
    for (int ks = 0; ks < 4; ++ks) {
        bf16x8 af[4], bfr[4];
        #pragma unroll
        for (int mt = 0; mt < 4; ++mt) {
            int r = wm*64 + mt*16 + frow;
            af[mt] = *(const bf16x8*)((char*)Al + r*256 + ((ks*64 + kg*16) ^ ((r & 7) << 4)));
        }
        #pragma unroll
        for (int nt = 0; nt < 4; ++nt) {
            int r = wn*64 + nt*16 + frow;
            bfr[nt] = *(const bf16x8*)((char*)Bl + r*256 + ((ks*64 + kg*16) ^ ((r & 7) << 4)));
        }
        #pragma unroll
        for (int mt = 0; mt < 4; ++mt)
            #pragma unroll
            for (int nt = 0; nt < 4; ++nt)
                acc[mt][nt] = __builtin_amdgcn_mfma_f32_16x16x32_bf16(
                    af[mt], bfr[nt], acc[mt][nt], 0, 0, 0);
    }

    const int ccol  = lane & 15;
    const int crow0 = (lane >> 4) * 4;
    #pragma unroll
    for (int nt = 0; nt < 4; ++nt) {
        const int m = wn*64 + nt*16 + ccol;
        const int jj = op[h*128 + m];
        #pragma unroll
        for (int mt = 0; mt < 4; ++mt) {
            #pragma unroll
            for (int i = 0; i < 4; ++i) {
                const int c = c0 + wm*64 + mt*16 + crow0 + i;
                WoutT[(size_t)jj * 2048 + c] = (bf16_t)acc[mt][nt][i];
            }
        }
    }
}

// ======== fast DCT-4096 (Makhoul real-FFT) + input perm + freq select ========
// Math identical to r16 (absmax-verified); LDS indices padded i+(i>>5) to kill
// the power-of-2-stride bank conflicts (5.77e7/dispatch measured at r16).
#define PADI(i) ((i) + ((i) >> 5))
__global__ __launch_bounds__(256) void k_dct(const float* __restrict__ x,
                                             const int* __restrict__ ipinv,
                                             const int* __restrict__ act,
                                             const float* __restrict__ tab,
                                             bf16_t* __restrict__ xa) {
    __shared__ float re[2112];
    __shared__ float im[2112];
    const int tid = threadIdx.x;
    const float* xr = x + (size_t)blockIdx.x * 4096;

    // scatter: load coalesced, place at Makhoul/perm position
    auto scat = [&](int m, float val) {
        int p = (m & 1) ? (4095 - (m >> 1)) : (m >> 1);
        if (p & 1) im[PADI(p >> 1)] = val; else re[PADI(p >> 1)] = val;
    };
    #pragma unroll
    for (int b = 0; b < 4; ++b) {
        int r0 = (b*256 + tid) * 4;
        f32x4 xv = *(const f32x4*)(xr + r0);
        int4  mv = *(const int4*)(ipinv + r0);
        scat(mv.x, xv[0]); scat(mv.y, xv[1]); scat(mv.z, xv[2]); scat(mv.w, xv[3]);
    }
    __syncthreads();

    // 11-stage radix-2 DIF FFT, W = e^{-2pi i j/len}
    #pragma unroll
    for (int s = 0; s < 11; ++s) {
        const int sh = 10 - s;                  // log2(half)
        #pragma unroll
        for (int b = 0; b < 4; ++b) {
            int q  = b*256 + tid;               // butterfly id 0..1023
            int j  = q & ((1 << sh) - 1);
            int g  = q >> sh;
            int i0 = PADI((g << (sh + 1)) + j);
            int i1 = PADI((g << (sh + 1)) + j + (1 << sh));
            int u  = j << (3 + s);              // 16384*j/len
            float cw = tab[u];
            float sw = tab[(u + 12288) & 16383];
            float ar = re[i0], ai = im[i0];
            float br = re[i1], bi = im[i1];
            float dr = ar - br, di = ai - bi;
            re[i0] = ar + br; im[i0] = ai + bi;
            re[i1] = dr * cw + di * sw;
            im[i1] = di * cw - dr * sw;
        }
        __syncthreads();
    }

    // unpack + DCT twiddle + select + scale + store (coalesced in c)
    #pragma unroll
    for (int b = 0; b < 8; ++b) {
        int c = b*256 + tid;
        int k = act[c];
        int t, cj;
        if (k <= 2048) { t = k; cj = 0; } else { t = 4096 - k; cj = 1; }
        int k1 = t & 2047, km = (2048 - k1) & 2047;
        int p1 = PADI((int)(__brev((unsigned)k1) >> 21));
        int pm = PADI((int)(__brev((unsigned)km) >> 21));
        float ar = re[p1], ai = im[p1];
        float br = re[pm], bi = im[pm];
        float sr = ar + br, si = ai - bi;
        float dr = ar - br, di = ai + bi;
        int u = (4 * t) & 16383;
        float cw = tab[u], sw = tab[(u + 12288) & 16383];
        float vr = 0.5f * (sr - sw * dr + cw * di);
        float vi = 0.5f * (si - cw * dr - sw * di);
        if (cj) vi = -vi;
        float ck = tab[k], sk = tab[(k + 12288) & 16383];
        float X = ck * vr + sk * vi;
        float sc = (k == 0) ? 0.015625f : 0.02209708691f;   // sqrt(2/4096), k0 * 1/sqrt2
        xa[(size_t)blockIdx.x * 2048 + c] = (bf16_t)(X * sc);
    }
}

// ---------------- shared GEMM helpers ----------------
__device__ __forceinline__ bf16x8 read_frag(const bf16_t* lds, int row, int slot) {
    return *(const bf16x8*)(lds + (((row << 3) + (slot ^ (row & 7))) << 3));
}

// ====== 256x256 8-wave GEMM, BK=64, single barrier/iter (measured 4310 cy/tile) ======
// NOTE (r12 lesson): do NOT raise min-waves-per-EU -- acc[8][4] needs 128 VGPR.
template<int OUTF>   // 0 -> bf16 out, 1 -> f32 out + bias
__global__ __launch_bounds__(512, 2)
void gemm2s(const bf16_t* __restrict__ A, const bf16_t* __restrict__ Bt,
            void* __restrict__ Cp, const float* __restrict__ bias,
            int N, int K, int nbn) {
    __shared__ alignas(16) bf16_t lds[2][2][256*64];   // 128 KB

    const int tid  = threadIdx.x;
    const int lane = tid & 63;
    const int wid  = tid >> 6;
    const int wm   = wid >> 2;
    const int wn   = wid & 3;
    const int frow = lane & 15;
    const int kg   = lane >> 4;

    const int nwg = gridDim.x;
    const int cpx = nwg >> 3;
    const int swz = (blockIdx.x & 7) * cpx + (blockIdx.x >> 3);
    const int m0  = (swz / nbn) * 256;
    const int n0  = (swz % nbn) * 256;

    const bf16_t* gA = A  + (size_t)m0 * K;
    const bf16_t* gB = Bt + (size_t)n0 * K;

    auto stage = [&](int kt) {
        bf16_t* dA = &lds[kt & 1][0][0];
        bf16_t* dB = &lds[kt & 1][1][0];
        #pragma unroll
        for (int i = 0; i < 4; ++i) {
            int q = i*512 + tid, row = q >> 3, s = q & 7;
            gload_lds16(gA + (size_t)row*K + kt*64 + ((s ^ (row & 7)) << 3), dA + q*8);
        }
        #pragma unroll
        for (int i = 0; i < 4; ++i) {
            int q = i*512 + tid, row = q >> 3, s = q & 7;
            gload_lds16(gB + (size_t)row*K + kt*64 + ((s ^ (row & 7)) << 3), dB + q*8);
        }
    };

    f32x4 acc[8][4];
    #pragma unroll
    for (int a = 0; a < 8; ++a)
        #pragma unroll
        for (int b = 0; b < 4; ++b) acc[a][b] = (f32x4){0.f, 0.f, 0.f, 0.f};

    const int NT = K >> 6;
    stage(0);
    asm volatile("s_waitcnt vmcnt(0)" ::: "memory");
    __builtin_amdgcn_s_barrier();

    for (int t = 0; t < NT; ++t) {
        const int cur = t & 1;
        if (t + 1 < NT) stage(t + 1);

        const bf16_t* lA = &lds[cur][0][0];
        const bf16_t* lB = &lds[cur][1][0];
        __builtin_amdgcn_s_setprio(1);
        #pragma unroll
        for (int ks = 0; ks < 2; ++ks) {
            bf16x8 bfr[4];
            #pragma unroll
            for (int nt = 0; nt < 4; ++nt)
                bfr[nt] = read_frag(lB, wn*64 + nt*16 + frow, ks*4 + kg);
            #pragma unroll
            for (int mt = 0; mt < 8; ++mt) {
                bf16x8 af = read_frag(lA, wm*128 + mt*16 + frow, ks*4 + kg);
                #pragma unroll
                for (int nt = 0; nt < 4; ++nt)
                    acc[mt][nt] = __builtin_amdgcn_mfma_f32_16x16x32_bf16(
                        af, bfr[nt], acc[mt][nt], 0, 0, 0);
            }
        }
        __builtin_amdgcn_s_setprio(0);

        if (t + 1 < NT) {
            asm volatile("s_waitcnt vmcnt(0)" ::: "memory");   // free: issued pre-compute
            __builtin_amdgcn_s_barrier();                      // publish + WAR fence
        }
    }

    const int ccol  = lane & 15;
    const int crow0 = (lane >> 4) * 4;
    #pragma unroll
    for (int nt = 0; nt < 4; ++nt) {
        const int col = n0 + wn*64 + nt*16 + ccol;
        float bv = 0.f;
        if constexpr (OUTF == 1) bv = bias[col];
        #pragma unroll
        for (int mt = 0; mt < 8; ++mt) {
            const int row = m0 + wm*128 + mt*16 + crow0;
            #pragma unroll
            for (int i = 0; i < 4; ++i) {
                if constexpr (OUTF == 1)
                    ((float*)Cp)[(size_t)(row + i)*N + col] = acc[mt][nt][i] + bv;
                else
                    ((bf16_t*)Cp)[(size_t)(row + i)*N + col] = (bf16_t)acc[mt][nt][i];
            }
        }
    }
}

// ---------------- launcher ----------------
extern "C" void kernel_launch(void* const* d_in, const int* in_sizes, int n_in,
                              void* d_out, int out_size, void* d_ws, size_t ws_size,
                              hipStream_t stream) {
    (void)in_sizes; (void)n_in; (void)out_size;
    const float* x    = (const float*)d_in[0];
    const float* G1   = (const float*)d_in[1];
    const float* G2   = (const float*)d_in[2];
    const float* G3   = (const float*)d_in[3];
    const float* bias = (const float*)d_in[4];
    const int* perm_raw = (const int*)d_in[5];
    const int* act_raw  = (const int*)d_in[6];
    const int* oip_raw  = (const int*)d_in[7];

    if (ws_size < WS_SMALL) return;

    char* ws = (char*)d_ws;
    int*    perm  = (int*)   (ws + OFF_PERM);
    int*    act   = (int*)   (ws + OFF_ACT);
    int*    oip   = (int*)   (ws + OFF_OIP);
    int*    op    = (int*)   (ws + OFF_OP);
    int*    ipinv = (int*)   (ws + OFF_IPINV);
    bf16_t* DhT   = (bf16_t*)(ws + OFF_DHT);
    float*  tab   = (float*) (ws + OFF_TAB);
    float*  T     = (float*) (ws + OFF_T);
    float*  Amat  = (float*) (ws + OFF_AM);
    bf16_t* WoutT = (bf16_t*)(ws + OFF_WOUT);
    bf16_t* xa    = (bf16_t*)(ws + OFF_XA_S);   // overlays dead T/Amat during main

    // ---- prep (weights) ----
    k_norm_idx<<<16, 256, 0, stream>>>(perm_raw, act_raw, oip_raw, perm, act, oip);
    k_invert  <<<16, 256, 0, stream>>>(oip, perm, op, ipinv);
    k_costab  <<<64, 256, 0, stream>>>(tab);
    k_dht     <<<64, 256, 0, stream>>>(tab, DhT);
    k_build_T <<<1024, 256, 0, stream>>>(G2, G3, T);
    k_build_A <<<2048, 256, 0, stream>>>(G1, T, Amat);
    k_wout_mfma<<<dim3(32, 16), 256, 0, stream>>>(Amat, DhT, op, WoutT);

    // ---- main: two M-halves; fast DCT replaces cvt+GEMM1 ----
    for (int h = 0; h < 2; ++h) {
        const float* xh = x + (size_t)h * MHALF * IN_F;
        float* outh = (float*)d_out + (size_t)h * MHALF * OUT_F;
        // xa[8192][2048] = orthonormal-DCT(xp)[act] via Makhoul real-FFT
        k_dct<<<MHALF, 256, 0, stream>>>(xh, ipinv, act, tab, xa);
        // GEMM2: out[8192][4096] = xa @ WoutT^T + bias   (32 x 16 = 512 wgs)
        gemm2s<1><<<512, 512, 0, stream>>>(xa, WoutT, (void*)outh, bias,
                                           OUT_F, NACT, OUT_F/256);
    }
}

// Round 19
// 617.248 us; speedup vs baseline: 1.0706x; 1.0706x over previous
//
#include <hip/hip_runtime.h>
#include <cstdint>
#include <cstddef>

typedef __bf16 bf16_t;
typedef float f32x4 __attribute__((ext_vector_type(4)));
typedef __bf16 bf16x8 __attribute__((ext_vector_type(8)));

// ---------------- problem constants ----------------
#define TOKENS      16384
#define IN_F        4096
#define OUT_F       4096
#define NACT        2048
#define MHALF       8192

// ---------------- workspace layout (bytes) ----------------
static constexpr size_t OFF_PERM  = 0;                      // 4096 * 4
static constexpr size_t OFF_ACT   = 16384;                  // 2048 * 4
static constexpr size_t OFF_OIP   = 24576;                  // 4096 * 4
static constexpr size_t OFF_OP    = 40960;                  // 4096 * 4
static constexpr size_t OFF_IPINV = 57344;                  // 4096 * 4
static constexpr size_t OFF_DHT   = 73728;                  // 128*128 * 2 (bf16)
static constexpr size_t OFF_TAB   = 106496;                 // 16384 * 4 cos table
static constexpr size_t OFF_T     = 172032;                 // 8 MB
static constexpr size_t OFF_AM    = OFF_T    + 8388608;     // 32 MB
static constexpr size_t OFF_WOUT  = OFF_AM   + 33554432;    // 16 MB
static constexpr size_t WS_SMALL  = OFF_WOUT + 16777216;    // ~59 MB
// xa-half (32 MB) overlays dead T+Amat region during main phase
static constexpr size_t OFF_XA_S  = OFF_T;

// ---------------- helpers ----------------
__device__ __forceinline__ void gload_lds16(const void* gsrc, void* ldsdst) {
    __builtin_amdgcn_global_load_lds(
        (__attribute__((address_space(1))) void*)(uintptr_t)gsrc,
        (__attribute__((address_space(3))) void*)(uint32_t)(uintptr_t)ldsdst,
        16, 0, 0);
}

__device__ __forceinline__ int is_i64_flag(const int* p) {
    int s = 0;
    #pragma unroll
    for (int i = 1; i < 64; i += 2) s |= p[i];
    return s == 0;
}

// ---------------- index normalization (int64-or-int32 -> int32) ----------------
__global__ void k_norm_idx(const int* __restrict__ perm_raw,
                           const int* __restrict__ act_raw,
                           const int* __restrict__ oip_raw,
                           int* __restrict__ perm, int* __restrict__ act,
                           int* __restrict__ oip) {
    int i = blockIdx.x * blockDim.x + threadIdx.x;
    int p64 = is_i64_flag(perm_raw);
    int a64 = is_i64_flag(act_raw);
    int o64 = is_i64_flag(oip_raw);
    if (i < 4096) perm[i] = p64 ? perm_raw[2*i] : perm_raw[i];
    if (i < 2048) act[i]  = a64 ? act_raw[2*i]  : act_raw[i];
    if (i < 4096) oip[i]  = o64 ? oip_raw[2*i]  : oip_raw[i];
}

__global__ void k_invert(const int* __restrict__ oip, const int* __restrict__ perm,
                         int* __restrict__ op, int* __restrict__ ipinv) {
    int j = blockIdx.x * 256 + threadIdx.x;
    if (j < 4096) {
        op[oip[j]]     = j;   // forward output perm
        ipinv[perm[j]] = j;   // inverse input perm
    }
}

// ---------------- cos table: tab[i] = cos(pi * i / 8192), i in [0,16384) ----------------
// sin(pi*t/8192) = cos(pi*t/8192 + 3pi/2) = tab[(t + 12288) & 16383]
__global__ void k_costab(float* __restrict__ tab) {
    int i = blockIdx.x * 256 + threadIdx.x;    // 64 blocks
    tab[i] = cosf((float)i * 3.834951969e-4f);
}

// ---------------- DCT-128 transpose table, bf16: DhT[m][k] = Dh[k][m] ----------------
__global__ void k_dht(const float* __restrict__ tab, bf16_t* __restrict__ DhT) {
    int idx = blockIdx.x * 256 + threadIdx.x;   // 64 blocks
    int m = idx >> 7, k = idx & 127;
    unsigned ph = ((unsigned)(2*m + 1) * (unsigned)k) & 511u;   // period 4n = 512
    float v = 0.125f * tab[ph << 5];                            // cos(pi*ph/256)
    if (k == 0) v *= 0.70710678119f;
    DhT[m*128 + k] = (bf16_t)v;
}

// ---------------- T[r,j,q,k,u] = sum_s G2[r,j,q,s] * G3[s,k,u] ----------------
__global__ __launch_bounds__(256) void k_build_T(const float* __restrict__ G2,
                                                 const float* __restrict__ G3,
                                                 float* __restrict__ T) {
    __shared__ alignas(16) float g3s[64*8*16];   // 32 KB
    __shared__ float g2t[64*16];                 // [s][q], 4 KB
    int rj = blockIdx.x;                          // 1024 blocks: r*16 + j
    int r = rj >> 4, j = rj & 15;
    for (int idx = threadIdx.x; idx < 8192; idx += 256) g3s[idx] = G3[idx];
    for (int idx = threadIdx.x; idx < 1024; idx += 256) {
        int s = idx >> 4, q = idx & 15;
        g2t[idx] = G2[((size_t)((r*16 + j)*16 + q))*64 + s];
    }
    __syncthreads();
    int q = threadIdx.x >> 4, u = threadIdx.x & 15;
    float acc[8] = {0.f};
    for (int s = 0; s < 64; ++s) {
        float g2 = g2t[s*16 + q];
        #pragma unroll
        for (int k = 0; k < 8; ++k) acc[k] += g2 * g3s[(s*8 + k)*16 + u];
    }
    size_t base = ((size_t)((r*16 + j)*16 + q) * 8) * 16 + u;
    #pragma unroll
    for (int k = 0; k < 8; ++k) T[base + k*16] = acc[k];
}

// ---------------- A[cin][cout] = sum_r G1[i,p,r] * T[r,j,q,k,u] ----------------
__global__ __launch_bounds__(256) void k_build_A(const float* __restrict__ G1,
                                                 const float* __restrict__ T,
                                                 float* __restrict__ Amat) {
    __shared__ alignas(16) float Tl[64*16*16];   // [r][q][slot-swizzled], 64 KB
    __shared__ float g1t[64*16];                 // [r][p], 4 KB
    int cin = blockIdx.x;                         // 2048 blocks
    int i = cin >> 7, j = (cin >> 3) & 15, k = cin & 7;
    #pragma unroll
    for (int it = 0; it < 16; ++it) {
        int idx = it*256 + threadIdx.x;          // f32x4 index, 0..4095
        int slot = idx & 3, q = (idx >> 2) & 15, r = idx >> 6;
        f32x4 tv = *(const f32x4*)&T[(((((size_t)r*16 + j)*16 + q)*8) + k)*16 + slot*4];
        *(f32x4*)&Tl[(r*16 + q)*16 + ((slot ^ ((q >> 1) & 3)) << 2)] = tv;
    }
    for (int idx = threadIdx.x; idx < 1024; idx += 256) {
        int r = idx >> 4, p = idx & 15;
        g1t[idx] = G1[(i*16 + p)*64 + r];
    }
    __syncthreads();
    int p = threadIdx.x >> 4, q = threadIdx.x & 15;
    int qs = (q >> 1) & 3;
    f32x4 acc4[4];
    #pragma unroll
    for (int a = 0; a < 4; ++a) acc4[a] = (f32x4){0.f, 0.f, 0.f, 0.f};
    for (int r = 0; r < 64; ++r) {
        float g = g1t[r*16 + p];
        #pragma unroll
        for (int ub = 0; ub < 4; ++ub) {         // static acc index, runtime address
            f32x4 tv = *(const f32x4*)&Tl[(r*16 + q)*16 + ((ub ^ qs) << 2)];
            acc4[ub] += tv * g;
        }
    }
    size_t base = (size_t)cin * 4096 + p*256 + q*16;
    #pragma unroll
    for (int ub = 0; ub < 4; ++ub) *(f32x4*)&Amat[base + ub*4] = acc4[ub];
}

// ---- WoutT via MFMA: Out[128c][128m] = A_blk[c][k](bf16) x DhT[m][k](bf16)^T ----
__global__ __launch_bounds__(256) void k_wout_mfma(const float* __restrict__ Amat,
                                                   const bf16_t* __restrict__ DhT,
                                                   const int* __restrict__ op,
                                                   bf16_t* __restrict__ WoutT) {
    __shared__ alignas(16) bf16_t Al[128*128];   // 32 KB  [c][k]
    __shared__ alignas(16) bf16_t Bl[128*128];   // 32 KB  [m][k]
    const int h  = blockIdx.x;
    const int c0 = blockIdx.y * 128;
    const int t = threadIdx.x, lane = t & 63, wv = t >> 6;
    const int wm = wv >> 1, wn = wv & 1;
    const int frow = lane & 15, kg = lane >> 4;

    #pragma unroll
    for (int it = 0; it < 8; ++it) {
        int idx = it*256 + t;                    // 0..2047
        int row = idx >> 4, slot = idx & 15;
        int dst = row*256 + ((slot*16) ^ ((row & 7) << 4));   // byte offset
        const float* s = Amat + (size_t)(c0 + row)*4096 + h*128 + slot*8;
        f32x4 v0 = *(const f32x4*)s;
        f32x4 v1 = *(const f32x4*)(s + 4);
        bf16x8 av;
        av[0]=(bf16_t)v0[0]; av[1]=(bf16_t)v0[1]; av[2]=(bf16_t)v0[2]; av[3]=(bf16_t)v0[3];
        av[4]=(bf16_t)v1[0]; av[5]=(bf16_t)v1[1]; av[6]=(bf16_t)v1[2]; av[7]=(bf16_t)v1[3];
        *(bf16x8*)((char*)Al + dst) = av;
        bf16x8 dv = *(const bf16x8*)(DhT + row*128 + slot*8);
        *(bf16x8*)((char*)Bl + dst) = dv;
    }
    __syncthreads();

    f32x4 acc[4][4];
    #pragma unroll
    for (int a = 0; a < 4; ++a)
        #pragma unroll
        for (int b = 0; b < 4; ++b) acc[a][b] = (f32x4){0.f, 0.f, 0.f, 0.f};

    #pragma unroll
    for (int ks = 0; ks < 4; ++ks) {
        bf16x8 af[4], bfr[4];
        #pragma unroll
        for (int mt = 0; mt < 4; ++mt) {
            int r = wm*64 + mt*16 + frow;
            af[mt] = *(const bf16x8*)((char*)Al + r*256 + ((ks*64 + kg*16) ^ ((r & 7) << 4)));
        }
        #pragma unroll
        for (int nt = 0; nt < 4; ++nt) {
            int r = wn*64 + nt*16 + frow;
            bfr[nt] = *(const bf16x8*)((char*)Bl + r*256 + ((ks*64 + kg*16) ^ ((r & 7) << 4)));
        }
        #pragma unroll
        for (int mt = 0; mt < 4; ++mt)
            #pragma unroll
            for (int nt = 0; nt < 4; ++nt)
                acc[mt][nt] = __builtin_amdgcn_mfma_f32_16x16x32_bf16(
                    af[mt], bfr[nt], acc[mt][nt], 0, 0, 0);
    }

    const int ccol  = lane & 15;
    const int crow0 = (lane >> 4) * 4;
    #pragma unroll
    for (int nt = 0; nt < 4; ++nt) {
        const int m = wn*64 + nt*16 + ccol;
        const int jj = op[h*128 + m];
        #pragma unroll
        for (int mt = 0; mt < 4; ++mt) {
            #pragma unroll
            for (int i = 0; i < 4; ++i) {
                const int c = c0 + wm*64 + mt*16 + crow0 + i;
                WoutT[(size_t)jj * 2048 + c] = (bf16_t)acc[mt][nt][i];
            }
        }
    }
}

// ======== fast DCT-4096 (Makhoul real-FFT) + input perm + freq select ========
// r16/r18-validated radix-2 network; stages now FUSED IN PAIRS in registers
// (identical in-place positions & twiddles -> numerically equivalent), halving
// LDS traffic (352 -> 192 b32 ops/thread) and barriers (12 -> 8).
// Twiddle identities: pair (i+h/2, i+3h/2) at stage s uses W(u+4096) = (-sin, cos);
// both stage-(s+1) pairs use W(2u).  Padded indices i+(i>>5) (r18, -4x conflicts).
#define PADI(i) ((i) + ((i) >> 5))
__global__ __launch_bounds__(256) void k_dct(const float* __restrict__ x,
                                             const int* __restrict__ ipinv,
                                             const int* __restrict__ act,
                                             const float* __restrict__ tab,
                                             bf16_t* __restrict__ xa) {
    __shared__ float re[2112];
    __shared__ float im[2112];
    const int tid = threadIdx.x;
    const float* xr = x + (size_t)blockIdx.x * 4096;

    // scatter: load coalesced, place at Makhoul/perm position
    auto scat = [&](int m, float val) {
        int p = (m & 1) ? (4095 - (m >> 1)) : (m >> 1);
        if (p & 1) im[PADI(p >> 1)] = val; else re[PADI(p >> 1)] = val;
    };
    #pragma unroll
    for (int b = 0; b < 4; ++b) {
        int r0 = (b*256 + tid) * 4;
        f32x4 xv = *(const f32x4*)(xr + r0);
        int4  mv = *(const int4*)(ipinv + r0);
        scat(mv.x, xv[0]); scat(mv.y, xv[1]); scat(mv.z, xv[2]); scat(mv.w, xv[3]);
    }
    __syncthreads();

    // 5 fused double-stages: s = 0,2,4,6,8 (sh = 10-s >= 2)
    #pragma unroll
    for (int ds = 0; ds < 5; ++ds) {
        const int s  = 2*ds;
        const int sh = 10 - s;
        #pragma unroll
        for (int b = 0; b < 2; ++b) {
            int q  = b*256 + tid;                    // group id 0..511
            int j  = q & ((1 << (sh-1)) - 1);
            int g  = q >> (sh - 1);
            int i0 = (g << (sh + 1)) + j;
            int p0 = PADI(i0);
            int p1 = PADI(i0 + (1 << (sh-1)));
            int p2 = PADI(i0 + (1 << sh));
            int p3 = PADI(i0 + (1 << sh) + (1 << (sh-1)));
            int ua = j << (3 + s);                   // < 8192
            float ca = tab[ua], sa = tab[(ua + 12288) & 16383];
            int uc = ua << 1;                        // < 16384
            float cc = tab[uc], sc = tab[(uc + 12288) & 16383];
            float r0v=re[p0], m0v=im[p0], r1v=re[p1], m1v=im[p1];
            float r2v=re[p2], m2v=im[p2], r3v=re[p3], m3v=im[p3];
            // stage s: pairs (0,2) with W(ua), (1,3) with W(ua+4096)=(-sa,ca)
            float t0r=r0v+r2v, t0m=m0v+m2v;
            float dr=r0v-r2v,  dm=m0v-m2v;
            float t2r=dr*ca+dm*sa, t2m=dm*ca-dr*sa;
            float t1r=r1v+r3v, t1m=m1v+m3v;
            float er=r1v-r3v,  em=m1v-m3v;
            float t3r=em*ca-er*sa, t3m=-em*sa-er*ca;
            // stage s+1: pairs (0,1) and (2,3), both with W(uc)
            re[p0]=t0r+t1r; im[p0]=t0m+t1m;
            float fr=t0r-t1r, fm=t0m-t1m;
            re[p1]=fr*cc+fm*sc; im[p1]=fm*cc-fr*sc;
            re[p2]=t2r+t3r; im[p2]=t2m+t3m;
            float gr=t2r-t3r, gm=t2m-t3m;
            re[p3]=gr*cc+gm*sc; im[p3]=gm*cc-gr*sc;
        }
        __syncthreads();
    }
    // final stage s=10 (h=1, twiddle-free)
    #pragma unroll
    for (int b = 0; b < 4; ++b) {
        int q = b*256 + tid;
        int p0 = PADI(2*q), p1 = PADI(2*q + 1);
        float ar=re[p0], am=im[p0], br=re[p1], bm=im[p1];
        re[p0]=ar+br; im[p0]=am+bm;
        re[p1]=ar-br; im[p1]=am-bm;
    }
    __syncthreads();

    // unpack + DCT twiddle + select + scale + store (coalesced in c)
    #pragma unroll
    for (int b = 0; b < 8; ++b) {
        int c = b*256 + tid;
        int k = act[c];
        int t, cj;
        if (k <= 2048) { t = k; cj = 0; } else { t = 4096 - k; cj = 1; }
        int k1 = t & 2047, km = (2048 - k1) & 2047;
        int p1 = PADI((int)(__brev((unsigned)k1) >> 21));
        int pm = PADI((int)(__brev((unsigned)km) >> 21));
        float ar = re[p1], ai = im[p1];
        float br = re[pm], bi = im[pm];
        float sr = ar + br, si = ai - bi;
        float dr = ar - br, di = ai + bi;
        int u = (4 * t) & 16383;
        float cw = tab[u], sw = tab[(u + 12288) & 16383];
        float vr = 0.5f * (sr - sw * dr + cw * di);
        float vi = 0.5f * (si - cw * dr - sw * di);
        if (cj) vi = -vi;
        float ck = tab[k], sk = tab[(k + 12288) & 16383];
        float X = ck * vr + sk * vi;
        float sc = (k == 0) ? 0.015625f : 0.02209708691f;   // sqrt(2/4096), k0 * 1/sqrt2
        xa[(size_t)blockIdx.x * 2048 + c] = (bf16_t)(X * sc);
    }
}

// ---------------- shared GEMM helpers ----------------
__device__ __forceinline__ bf16x8 read_frag(const bf16_t* lds, int row, int slot) {
    return *(const bf16x8*)(lds + (((row << 3) + (slot ^ (row & 7))) << 3));
}

// ====== 256x256 8-wave GEMM, BK=64, single barrier/iter (measured 4310 cy/tile) ======
// NOTE (r12 lesson): do NOT raise min-waves-per-EU -- acc[8][4] needs 128 VGPR.
template<int OUTF>   // 0 -> bf16 out, 1 -> f32 out + bias
__global__ __launch_bounds__(512, 2)
void gemm2s(const bf16_t* __restrict__ A, const bf16_t* __restrict__ Bt,
            void* __restrict__ Cp, const float* __restrict__ bias,
            int N, int K, int nbn) {
    __shared__ alignas(16) bf16_t lds[2][2][256*64];   // 128 KB

    const int tid  = threadIdx.x;
    const int lane = tid & 63;
    const int wid  = tid >> 6;
    const int wm   = wid >> 2;
    const int wn   = wid & 3;
    const int frow = lane & 15;
    const int kg   = lane >> 4;

    const int nwg = gridDim.x;
    const int cpx = nwg >> 3;
    const int swz = (blockIdx.x & 7) * cpx + (blockIdx.x >> 3);
    const int m0  = (swz / nbn) * 256;
    const int n0  = (swz % nbn) * 256;

    const bf16_t* gA = A  + (size_t)m0 * K;
    const bf16_t* gB = Bt + (size_t)n0 * K;

    auto stage = [&](int kt) {
        bf16_t* dA = &lds[kt & 1][0][0];
        bf16_t* dB = &lds[kt & 1][1][0];
        #pragma unroll
        for (int i = 0; i < 4; ++i) {
            int q = i*512 + tid, row = q >> 3, s = q & 7;
            gload_lds16(gA + (size_t)row*K + kt*64 + ((s ^ (row & 7)) << 3), dA + q*8);
        }
        #pragma unroll
        for (int i = 0; i < 4; ++i) {
            int q = i*512 + tid, row = q >> 3, s = q & 7;
            gload_lds16(gB + (size_t)row*K + kt*64 + ((s ^ (row & 7)) << 3), dB + q*8);
        }
    };

    f32x4 acc[8][4];
    #pragma unroll
    for (int a = 0; a < 8; ++a)
        #pragma unroll
        for (int b = 0; b < 4; ++b) acc[a][b] = (f32x4){0.f, 0.f, 0.f, 0.f};

    const int NT = K >> 6;
    stage(0);
    asm volatile("s_waitcnt vmcnt(0)" ::: "memory");
    __builtin_amdgcn_s_barrier();

    for (int t = 0; t < NT; ++t) {
        const int cur = t & 1;
        if (t + 1 < NT) stage(t + 1);

        const bf16_t* lA = &lds[cur][0][0];
        const bf16_t* lB = &lds[cur][1][0];
        __builtin_amdgcn_s_setprio(1);
        #pragma unroll
        for (int ks = 0; ks < 2; ++ks) {
            bf16x8 bfr[4];
            #pragma unroll
            for (int nt = 0; nt < 4; ++nt)
                bfr[nt] = read_frag(lB, wn*64 + nt*16 + frow, ks*4 + kg);
            #pragma unroll
            for (int mt = 0; mt < 8; ++mt) {
                bf16x8 af = read_frag(lA, wm*128 + mt*16 + frow, ks*4 + kg);
                #pragma unroll
                for (int nt = 0; nt < 4; ++nt)
                    acc[mt][nt] = __builtin_amdgcn_mfma_f32_16x16x32_bf16(
                        af, bfr[nt], acc[mt][nt], 0, 0, 0);
            }
        }
        __builtin_amdgcn_s_setprio(0);

        if (t + 1 < NT) {
            asm volatile("s_waitcnt vmcnt(0)" ::: "memory");   // free: issued pre-compute
            __builtin_amdgcn_s_barrier();                      // publish + WAR fence
        }
    }

    const int ccol  = lane & 15;
    const int crow0 = (lane >> 4) * 4;
    #pragma unroll
    for (int nt = 0; nt < 4; ++nt) {
        const int col = n0 + wn*64 + nt*16 + ccol;
        float bv = 0.f;
        if constexpr (OUTF == 1) bv = bias[col];
        #pragma unroll
        for (int mt = 0; mt < 8; ++mt) {
            const int row = m0 + wm*128 + mt*16 + crow0;
            #pragma unroll
            for (int i = 0; i < 4; ++i) {
                if constexpr (OUTF == 1)
                    ((float*)Cp)[(size_t)(row + i)*N + col] = acc[mt][nt][i] + bv;
                else
                    ((bf16_t*)Cp)[(size_t)(row + i)*N + col] = (bf16_t)acc[mt][nt][i];
            }
        }
    }
}

// ---------------- launcher ----------------
extern "C" void kernel_launch(void* const* d_in, const int* in_sizes, int n_in,
                              void* d_out, int out_size, void* d_ws, size_t ws_size,
                              hipStream_t stream) {
    (void)in_sizes; (void)n_in; (void)out_size;
    const float* x    = (const float*)d_in[0];
    const float* G1   = (const float*)d_in[1];
    const float* G2   = (const float*)d_in[2];
    const float* G3   = (const float*)d_in[3];
    const float* bias = (const float*)d_in[4];
    const int* perm_raw = (const int*)d_in[5];
    const int* act_raw  = (const int*)d_in[6];
    const int* oip_raw  = (const int*)d_in[7];

    if (ws_size < WS_SMALL) return;

    char* ws = (char*)d_ws;
    int*    perm  = (int*)   (ws + OFF_PERM);
    int*    act   = (int*)   (ws + OFF_ACT);
    int*    oip   = (int*)   (ws + OFF_OIP);
    int*    op    = (int*)   (ws + OFF_OP);
    int*    ipinv = (int*)   (ws + OFF_IPINV);
    bf16_t* DhT   = (bf16_t*)(ws + OFF_DHT);
    float*  tab   = (float*) (ws + OFF_TAB);
    float*  T     = (float*) (ws + OFF_T);
    float*  Amat  = (float*) (ws + OFF_AM);
    bf16_t* WoutT = (bf16_t*)(ws + OFF_WOUT);
    bf16_t* xa    = (bf16_t*)(ws + OFF_XA_S);   // overlays dead T/Amat during main

    // ---- prep (weights) ----
    k_norm_idx<<<16, 256, 0, stream>>>(perm_raw, act_raw, oip_raw, perm, act, oip);
    k_invert  <<<16, 256, 0, stream>>>(oip, perm, op, ipinv);
    k_costab  <<<64, 256, 0, stream>>>(tab);
    k_dht     <<<64, 256, 0, stream>>>(tab, DhT);
    k_build_T <<<1024, 256, 0, stream>>>(G2, G3, T);
    k_build_A <<<2048, 256, 0, stream>>>(G1, T, Amat);
    k_wout_mfma<<<dim3(32, 16), 256, 0, stream>>>(Amat, DhT, op, WoutT);

    // ---- main: two M-halves; fast DCT replaces cvt+GEMM1 ----
    for (int h = 0; h < 2; ++h) {
        const float* xh = x + (size_t)h * MHALF * IN_F;
        float* outh = (float*)d_out + (size_t)h * MHALF * OUT_F;
        // xa[8192][2048] = orthonormal-DCT(xp)[act] via Makhoul real-FFT
        k_dct<<<MHALF, 256, 0, stream>>>(xh, ipinv, act, tab, xa);
        // GEMM2: out[8192][4096] = xa @ WoutT^T + bias   (32 x 16 = 512 wgs)
        gemm2s<1><<<512, 512, 0, stream>>>(xa, WoutT, (void*)outh, bias,
                                           OUT_F, NACT, OUT_F/256);
    }
}

// Round 20
// 615.236 us; speedup vs baseline: 1.0741x; 1.0033x over previous
//
#include <hip/hip_runtime.h>
#include <cstdint>
#include <cstddef>

typedef __bf16 bf16_t;
typedef float f32x4 __attribute__((ext_vector_type(4)));
typedef __bf16 bf16x8 __attribute__((ext_vector_type(8)));

// ---------------- problem constants ----------------
#define TOKENS      16384
#define IN_F        4096
#define OUT_F       4096
#define NACT        2048
#define MHALF       8192

// ---------------- workspace layout (bytes) ----------------
static constexpr size_t OFF_PERM  = 0;                      // 4096 * 4
static constexpr size_t OFF_ACT   = 16384;                  // 2048 * 4
static constexpr size_t OFF_OIP   = 24576;                  // 4096 * 4
static constexpr size_t OFF_OP    = 40960;                  // 4096 * 4
static constexpr size_t OFF_IPINV = 57344;                  // 4096 * 4
static constexpr size_t OFF_DHT   = 73728;                  // 128*128 * 2 (bf16)
static constexpr size_t OFF_TAB   = 106496;                 // 16384 * 4 cos table
static constexpr size_t OFF_T     = 172032;                 // 8 MB
static constexpr size_t OFF_AM    = OFF_T    + 8388608;     // 32 MB
static constexpr size_t OFF_WOUT  = OFF_AM   + 33554432;    // 16 MB
static constexpr size_t WS_SMALL  = OFF_WOUT + 16777216;    // ~59 MB
// xa-half (32 MB) overlays dead T+Amat region during main phase
static constexpr size_t OFF_XA_S  = OFF_T;

// ---------------- helpers ----------------
__device__ __forceinline__ void gload_lds16(const void* gsrc, void* ldsdst) {
    __builtin_amdgcn_global_load_lds(
        (__attribute__((address_space(1))) void*)(uintptr_t)gsrc,
        (__attribute__((address_space(3))) void*)(uint32_t)(uintptr_t)ldsdst,
        16, 0, 0);
}

__device__ __forceinline__ int is_i64_flag(const int* p) {
    int s = 0;
    #pragma unroll
    for (int i = 1; i < 64; i += 2) s |= p[i];
    return s == 0;
}

// ---------------- index normalization (int64-or-int32 -> int32) ----------------
__global__ void k_norm_idx(const int* __restrict__ perm_raw,
                           const int* __restrict__ act_raw,
                           const int* __restrict__ oip_raw,
                           int* __restrict__ perm, int* __restrict__ act,
                           int* __restrict__ oip) {
    int i = blockIdx.x * blockDim.x + threadIdx.x;
    int p64 = is_i64_flag(perm_raw);
    int a64 = is_i64_flag(act_raw);
    int o64 = is_i64_flag(oip_raw);
    if (i < 4096) perm[i] = p64 ? perm_raw[2*i] : perm_raw[i];
    if (i < 2048) act[i]  = a64 ? act_raw[2*i]  : act_raw[i];
    if (i < 4096) oip[i]  = o64 ? oip_raw[2*i]  : oip_raw[i];
}

__global__ void k_invert(const int* __restrict__ oip, const int* __restrict__ perm,
                         int* __restrict__ op, int* __restrict__ ipinv) {
    int j = blockIdx.x * 256 + threadIdx.x;
    if (j < 4096) {
        op[oip[j]]     = j;   // forward output perm
        ipinv[perm[j]] = j;   // inverse input perm
    }
}

// ---------------- cos table: tab[i] = cos(pi * i / 8192), i in [0,16384) ----------------
// sin(pi*t/8192) = cos(pi*t/8192 + 3pi/2) = tab[(t + 12288) & 16383]
__global__ void k_costab(float* __restrict__ tab) {
    int i = blockIdx.x * 256 + threadIdx.x;    // 64 blocks
    tab[i] = cosf((float)i * 3.834951969e-4f);
}

// ---------------- DCT-128 transpose table, bf16: DhT[m][k] = Dh[k][m] ----------------
__global__ void k_dht(const float* __restrict__ tab, bf16_t* __restrict__ DhT) {
    int idx = blockIdx.x * 256 + threadIdx.x;   // 64 blocks
    int m = idx >> 7, k = idx & 127;
    unsigned ph = ((unsigned)(2*m + 1) * (unsigned)k) & 511u;   // period 4n = 512
    float v = 0.125f * tab[ph << 5];                            // cos(pi*ph/256)
    if (k == 0) v *= 0.70710678119f;
    DhT[m*128 + k] = (bf16_t)v;
}

// ---------------- T[r,j,q,k,u] = sum_s G2[r,j,q,s] * G3[s,k,u] ----------------
__global__ __launch_bounds__(256) void k_build_T(const float* __restrict__ G2,
                                                 const float* __restrict__ G3,
                                                 float* __restrict__ T) {
    __shared__ alignas(16) float g3s[64*8*16];   // 32 KB
    __shared__ float g2t[64*16];                 // [s][q], 4 KB
    int rj = blockIdx.x;                          // 1024 blocks: r*16 + j
    int r = rj >> 4, j = rj & 15;
    for (int idx = threadIdx.x; idx < 8192; idx += 256) g3s[idx] = G3[idx];
    for (int idx = threadIdx.x; idx < 1024; idx += 256) {
        int s = idx >> 4, q = idx & 15;
        g2t[idx] = G2[((size_t)((r*16 + j)*16 + q))*64 + s];
    }
    __syncthreads();
    int q = threadIdx.x >> 4, u = threadIdx.x & 15;
    float acc[8] = {0.f};
    for (int s = 0; s < 64; ++s) {
        float g2 = g2t[s*16 + q];
        #pragma unroll
        for (int k = 0; k < 8; ++k) acc[k] += g2 * g3s[(s*8 + k)*16 + u];
    }
    size_t base = ((size_t)((r*16 + j)*16 + q) * 8) * 16 + u;
    #pragma unroll
    for (int k = 0; k < 8; ++k) T[base + k*16] = acc[k];
}

// ---------------- A[cin][cout] = sum_r G1[i,p,r] * T[r,j,q,k,u] ----------------
__global__ __launch_bounds__(256) void k_build_A(const float* __restrict__ G1,
                                                 const float* __restrict__ T,
                                                 float* __restrict__ Amat) {
    __shared__ alignas(16) float Tl[64*16*16];   // [r][q][slot-swizzled], 64 KB
    __shared__ float g1t[64*16];                 // [r][p], 4 KB
    int cin = blockIdx.x;                         // 2048 blocks
    int i = cin >> 7, j = (cin >> 3) & 15, k = cin & 7;
    #pragma unroll
    for (int it = 0; it < 16; ++it) {
        int idx = it*256 + threadIdx.x;          // f32x4 index, 0..4095
        int slot = idx & 3, q = (idx >> 2) & 15, r = idx >> 6;
        f32x4 tv = *(const f32x4*)&T[(((((size_t)r*16 + j)*16 + q)*8) + k)*16 + slot*4];
        *(f32x4*)&Tl[(r*16 + q)*16 + ((slot ^ ((q >> 1) & 3)) << 2)] = tv;
    }
    for (int idx = threadIdx.x; idx < 1024; idx += 256) {
        int r = idx >> 4, p = idx & 15;
        g1t[idx] = G1[(i*16 + p)*64 + r];
    }
    __syncthreads();
    int p = threadIdx.x >> 4, q = threadIdx.x & 15;
    int qs = (q >> 1) & 3;
    f32x4 acc4[4];
    #pragma unroll
    for (int a = 0; a < 4; ++a) acc4[a] = (f32x4){0.f, 0.f, 0.f, 0.f};
    for (int r = 0; r < 64; ++r) {
        float g = g1t[r*16 + p];
        #pragma unroll
        for (int ub = 0; ub < 4; ++ub) {         // static acc index, runtime address
            f32x4 tv = *(const f32x4*)&Tl[(r*16 + q)*16 + ((ub ^ qs) << 2)];
            acc4[ub] += tv * g;
        }
    }
    size_t base = (size_t)cin * 4096 + p*256 + q*16;
    #pragma unroll
    for (int ub = 0; ub < 4; ++ub) *(f32x4*)&Amat[base + ub*4] = acc4[ub];
}

// ---- WoutT via MFMA: Out[128c][128m] = A_blk[c][k](bf16) x DhT[m][k](bf16)^T ----
__global__ __launch_bounds__(256) void k_wout_mfma(const float* __restrict__ Amat,
                                                   const bf16_t* __restrict__ DhT,
                                                   const int* __restrict__ op,
                                                   bf16_t* __restrict__ WoutT) {
    __shared__ alignas(16) bf16_t Al[128*128];   // 32 KB  [c][k]
    __shared__ alignas(16) bf16_t Bl[128*128];   // 32 KB  [m][k]
    const int h  = blockIdx.x;
    const int c0 = blockIdx.y * 128;
    const int t = threadIdx.x, lane = t & 63, wv = t >> 6;
    const int wm = wv >> 1, wn = wv & 1;
    const int frow = lane & 15, kg = lane >> 4;

    #pragma unroll
    for (int it = 0; it < 8; ++it) {
        int idx = it*256 + t;                    // 0..2047
        int row = idx >> 4, slot = idx & 15;
        int dst = row*256 + ((slot*16) ^ ((row & 7) << 4));   // byte offset
        const float* s = Amat + (size_t)(c0 + row)*4096 + h*128 + slot*8;
        f32x4 v0 = *(const f32x4*)s;
        f32x4 v1 = *(const f32x4*)(s + 4);
        bf16x8 av;
        av[0]=(bf16_t)v0[0]; av[1]=(bf16_t)v0[1]; av[2]=(bf16_t)v0[2]; av[3]=(bf16_t)v0[3];
        av[4]=(bf16_t)v1[0]; av[5]=(bf16_t)v1[1]; av[6]=(bf16_t)v1[2]; av[7]=(bf16_t)v1[3];
        *(bf16x8*)((char*)Al + dst) = av;
        bf16x8 dv = *(const bf16x8*)(DhT + row*128 + slot*8);
        *(bf16x8*)((char*)Bl + dst) = dv;
    }
    __syncthreads();

    f32x4 acc[4][4];
    #pragma unroll
    for (int a = 0; a < 4; ++a)
        #pragma unroll
        for (int b = 0; b < 4; ++b) acc[a][b] = (f32x4){0.f, 0.f, 0.f, 0.f};

    #pragma unroll
    for (int ks = 0; ks < 4; ++ks) {
        bf16x8 af[4], bfr[4];
        #pragma unroll
        for (int mt = 0; mt < 4; ++mt) {
            int r = wm*64 + mt*16 + frow;
            af[mt] = *(const bf16x8*)((char*)Al + r*256 + ((ks*64 + kg*16) ^ ((r & 7) << 4)));
        }
        #pragma unroll
        for (int nt = 0; nt < 4; ++nt) {
            int r = wn*64 + nt*16 + frow;
            bfr[nt] = *(const bf16x8*)((char*)Bl + r*256 + ((ks*64 + kg*16) ^ ((r & 7) << 4)));
        }
        #pragma unroll
        for (int mt = 0; mt < 4; ++mt)
            #pragma unroll
            for (int nt = 0; nt < 4; ++nt)
                acc[mt][nt] = __builtin_amdgcn_mfma_f32_16x16x32_bf16(
                    af[mt], bfr[nt], acc[mt][nt], 0, 0, 0);
    }

    const int ccol  = lane & 15;
    const int crow0 = (lane >> 4) * 4;
    #pragma unroll
    for (int nt = 0; nt < 4; ++nt) {
        const int m = wn*64 + nt*16 + ccol;
        const int jj = op[h*128 + m];
        #pragma unroll
        for (int mt = 0; mt < 4; ++mt) {
            #pragma unroll
            for (int i = 0; i < 4; ++i) {
                const int c = c0 + wm*64 + mt*16 + crow0 + i;
                WoutT[(size_t)jj * 2048 + c] = (bf16_t)acc[mt][nt][i];
            }
        }
    }
}

// ======== fast DCT-4096 (Makhoul real-FFT) + input perm + freq select ========
// r19-validated fused double-stage network; LDS now holds complex float2 so each
// butterfly access is one ds_*_b64 (LDS ops ~halved again). Same math, same order.
// Pad for 8B elements: PADF(i) = i + (i>>4) (16 float2 = 32 banks per row).
#define PADF(i) ((i) + ((i) >> 4))
__global__ __launch_bounds__(256) void k_dct(const float* __restrict__ x,
                                             const int* __restrict__ ipinv,
                                             const int* __restrict__ act,
                                             const float* __restrict__ tab,
                                             bf16_t* __restrict__ xa) {
    __shared__ float2 cz[2176];    // 2048 complex + pad, 17.4 KB
    const int tid = threadIdx.x;
    const float* xr = x + (size_t)blockIdx.x * 4096;

    // scatter: load coalesced, place at Makhoul/perm position (.x=re, .y=im)
    auto scat = [&](int m, float val) {
        int p = (m & 1) ? (4095 - (m >> 1)) : (m >> 1);
        if (p & 1) cz[PADF(p >> 1)].y = val; else cz[PADF(p >> 1)].x = val;
    };
    #pragma unroll
    for (int b = 0; b < 4; ++b) {
        int r0 = (b*256 + tid) * 4;
        f32x4 xv = *(const f32x4*)(xr + r0);
        int4  mv = *(const int4*)(ipinv + r0);
        scat(mv.x, xv[0]); scat(mv.y, xv[1]); scat(mv.z, xv[2]); scat(mv.w, xv[3]);
    }
    __syncthreads();

    // 5 fused double-stages: s = 0,2,4,6,8 (sh = 10-s >= 2)
    #pragma unroll
    for (int ds = 0; ds < 5; ++ds) {
        const int s  = 2*ds;
        const int sh = 10 - s;
        #pragma unroll
        for (int b = 0; b < 2; ++b) {
            int q  = b*256 + tid;                    // group id 0..511
            int j  = q & ((1 << (sh-1)) - 1);
            int g  = q >> (sh - 1);
            int i0 = (g << (sh + 1)) + j;
            int p0 = PADF(i0);
            int p1 = PADF(i0 + (1 << (sh-1)));
            int p2 = PADF(i0 + (1 << sh));
            int p3 = PADF(i0 + (1 << sh) + (1 << (sh-1)));
            int ua = j << (3 + s);                   // < 8192
            float ca = tab[ua], sa = tab[(ua + 12288) & 16383];
            int uc = ua << 1;                        // < 16384
            float cc = tab[uc], sc = tab[(uc + 12288) & 16383];
            float2 v0 = cz[p0], v1 = cz[p1], v2 = cz[p2], v3 = cz[p3];
            // stage s: pairs (0,2) with W(ua), (1,3) with W(ua+4096)=(-sa,ca)
            float t0r=v0.x+v2.x, t0m=v0.y+v2.y;
            float dr=v0.x-v2.x,  dm=v0.y-v2.y;
            float t2r=dr*ca+dm*sa, t2m=dm*ca-dr*sa;
            float t1r=v1.x+v3.x, t1m=v1.y+v3.y;
            float er=v1.x-v3.x,  em=v1.y-v3.y;
            float t3r=em*ca-er*sa, t3m=-em*sa-er*ca;
            // stage s+1: pairs (0,1) and (2,3), both with W(uc)
            float fr=t0r-t1r, fm=t0m-t1m;
            float gr=t2r-t3r, gm=t2m-t3m;
            cz[p0] = make_float2(t0r+t1r, t0m+t1m);
            cz[p1] = make_float2(fr*cc+fm*sc, fm*cc-fr*sc);
            cz[p2] = make_float2(t2r+t3r, t2m+t3m);
            cz[p3] = make_float2(gr*cc+gm*sc, gm*cc-gr*sc);
        }
        __syncthreads();
    }
    // final stage s=10 (h=1, twiddle-free)
    #pragma unroll
    for (int b = 0; b < 4; ++b) {
        int q = b*256 + tid;
        int p0 = PADF(2*q), p1 = PADF(2*q + 1);
        float2 a = cz[p0], bb = cz[p1];
        cz[p0] = make_float2(a.x + bb.x, a.y + bb.y);
        cz[p1] = make_float2(a.x - bb.x, a.y - bb.y);
    }
    __syncthreads();

    // unpack + DCT twiddle + select + scale + store (coalesced in c)
    #pragma unroll
    for (int b = 0; b < 8; ++b) {
        int c = b*256 + tid;
        int k = act[c];
        int t, cj;
        if (k <= 2048) { t = k; cj = 0; } else { t = 4096 - k; cj = 1; }
        int k1 = t & 2047, km = (2048 - k1) & 2047;
        int p1 = PADF((int)(__brev((unsigned)k1) >> 21));
        int pm = PADF((int)(__brev((unsigned)km) >> 21));
        float2 z1 = cz[p1], zm = cz[pm];
        float ar = z1.x, ai = z1.y;
        float br = zm.x, bi = zm.y;
        float sr = ar + br, si = ai - bi;
        float dr = ar - br, di = ai + bi;
        int u = (4 * t) & 16383;
        float cw = tab[u], sw = tab[(u + 12288) & 16383];
        float vr = 0.5f * (sr - sw * dr + cw * di);
        float vi = 0.5f * (si - cw * dr - sw * di);
        if (cj) vi = -vi;
        float ck = tab[k], sk = tab[(k + 12288) & 16383];
        float X = ck * vr + sk * vi;
        float sc = (k == 0) ? 0.015625f : 0.02209708691f;   // sqrt(2/4096), k0 * 1/sqrt2
        xa[(size_t)blockIdx.x * 2048 + c] = (bf16_t)(X * sc);
    }
}

// ---------------- shared GEMM helpers ----------------
__device__ __forceinline__ bf16x8 read_frag(const bf16_t* lds, int row, int slot) {
    return *(const bf16x8*)(lds + (((row << 3) + (slot ^ (row & 7))) << 3));
}

// ====== 256x256 8-wave GEMM, BK=64, single barrier/iter (measured 4310 cy/tile) ======
// NOTE (r12 lesson): do NOT raise min-waves-per-EU -- acc[8][4] needs 128 VGPR.
template<int OUTF>   // 0 -> bf16 out, 1 -> f32 out + bias
__global__ __launch_bounds__(512, 2)
void gemm2s(const bf16_t* __restrict__ A, const bf16_t* __restrict__ Bt,
            void* __restrict__ Cp, const float* __restrict__ bias,
            int N, int K, int nbn) {
    __shared__ alignas(16) bf16_t lds[2][2][256*64];   // 128 KB

    const int tid  = threadIdx.x;
    const int lane = tid & 63;
    const int wid  = tid >> 6;
    const int wm   = wid >> 2;
    const int wn   = wid & 3;
    const int frow = lane & 15;
    const int kg   = lane >> 4;

    const int nwg = gridDim.x;
    const int cpx = nwg >> 3;
    const int swz = (blockIdx.x & 7) * cpx + (blockIdx.x >> 3);
    const int m0  = (swz / nbn) * 256;
    const int n0  = (swz % nbn) * 256;

    const bf16_t* gA = A  + (size_t)m0 * K;
    const bf16_t* gB = Bt + (size_t)n0 * K;

    auto stage = [&](int kt) {
        bf16_t* dA = &lds[kt & 1][0][0];
        bf16_t* dB = &lds[kt & 1][1][0];
        #pragma unroll
        for (int i = 0; i < 4; ++i) {
            int q = i*512 + tid, row = q >> 3, s = q & 7;
            gload_lds16(gA + (size_t)row*K + kt*64 + ((s ^ (row & 7)) << 3), dA + q*8);
        }
        #pragma unroll
        for (int i = 0; i < 4; ++i) {
            int q = i*512 + tid, row = q >> 3, s = q & 7;
            gload_lds16(gB + (size_t)row*K + kt*64 + ((s ^ (row & 7)) << 3), dB + q*8);
        }
    };

    f32x4 acc[8][4];
    #pragma unroll
    for (int a = 0; a < 8; ++a)
        #pragma unroll
        for (int b = 0; b < 4; ++b) acc[a][b] = (f32x4){0.f, 0.f, 0.f, 0.f};

    const int NT = K >> 6;
    stage(0);
    asm volatile("s_waitcnt vmcnt(0)" ::: "memory");
    __builtin_amdgcn_s_barrier();

    for (int t = 0; t < NT; ++t) {
        const int cur = t & 1;
        if (t + 1 < NT) stage(t + 1);

        const bf16_t* lA = &lds[cur][0][0];
        const bf16_t* lB = &lds[cur][1][0];
        __builtin_amdgcn_s_setprio(1);
        #pragma unroll
        for (int ks = 0; ks < 2; ++ks) {
            bf16x8 bfr[4];
            #pragma unroll
            for (int nt = 0; nt < 4; ++nt)
                bfr[nt] = read_frag(lB, wn*64 + nt*16 + frow, ks*4 + kg);
            #pragma unroll
            for (int mt = 0; mt < 8; ++mt) {
                bf16x8 af = read_frag(lA, wm*128 + mt*16 + frow, ks*4 + kg);
                #pragma unroll
                for (int nt = 0; nt < 4; ++nt)
                    acc[mt][nt] = __builtin_amdgcn_mfma_f32_16x16x32_bf16(
                        af, bfr[nt], acc[mt][nt], 0, 0, 0);
            }
        }
        __builtin_amdgcn_s_setprio(0);

        if (t + 1 < NT) {
            asm volatile("s_waitcnt vmcnt(0)" ::: "memory");   // free: issued pre-compute
            __builtin_amdgcn_s_barrier();                      // publish + WAR fence
        }
    }

    const int ccol  = lane & 15;
    const int crow0 = (lane >> 4) * 4;
    #pragma unroll
    for (int nt = 0; nt < 4; ++nt) {
        const int col = n0 + wn*64 + nt*16 + ccol;
        float bv = 0.f;
        if constexpr (OUTF == 1) bv = bias[col];
        #pragma unroll
        for (int mt = 0; mt < 8; ++mt) {
            const int row = m0 + wm*128 + mt*16 + crow0;
            #pragma unroll
            for (int i = 0; i < 4; ++i) {
                if constexpr (OUTF == 1)
                    ((float*)Cp)[(size_t)(row + i)*N + col] = acc[mt][nt][i] + bv;
                else
                    ((bf16_t*)Cp)[(size_t)(row + i)*N + col] = (bf16_t)acc[mt][nt][i];
            }
        }
    }
}

// ---------------- launcher ----------------
extern "C" void kernel_launch(void* const* d_in, const int* in_sizes, int n_in,
                              void* d_out, int out_size, void* d_ws, size_t ws_size,
                              hipStream_t stream) {
    (void)in_sizes; (void)n_in; (void)out_size;
    const float* x    = (const float*)d_in[0];
    const float* G1   = (const float*)d_in[1];
    const float* G2   = (const float*)d_in[2];
    const float* G3   = (const float*)d_in[3];
    const float* bias = (const float*)d_in[4];
    const int* perm_raw = (const int*)d_in[5];
    const int* act_raw  = (const int*)d_in[6];
    const int* oip_raw  = (const int*)d_in[7];

    if (ws_size < WS_SMALL) return;

    char* ws = (char*)d_ws;
    int*    perm  = (int*)   (ws + OFF_PERM);
    int*    act   = (int*)   (ws + OFF_ACT);
    int*    oip   = (int*)   (ws + OFF_OIP);
    int*    op    = (int*)   (ws + OFF_OP);
    int*    ipinv = (int*)   (ws + OFF_IPINV);
    bf16_t* DhT   = (bf16_t*)(ws + OFF_DHT);
    float*  tab   = (float*) (ws + OFF_TAB);
    float*  T     = (float*) (ws + OFF_T);
    float*  Amat  = (float*) (ws + OFF_AM);
    bf16_t* WoutT = (bf16_t*)(ws + OFF_WOUT);
    bf16_t* xa    = (bf16_t*)(ws + OFF_XA_S);   // overlays dead T/Amat during main

    // ---- prep (weights) ----
    k_norm_idx<<<16, 256, 0, stream>>>(perm_raw, act_raw, oip_raw, perm, act, oip);
    k_invert  <<<16, 256, 0, stream>>>(oip, perm, op, ipinv);
    k_costab  <<<64, 256, 0, stream>>>(tab);
    k_dht     <<<64, 256, 0, stream>>>(tab, DhT);
    k_build_T <<<1024, 256, 0, stream>>>(G2, G3, T);
    k_build_A <<<2048, 256, 0, stream>>>(G1, T, Amat);
    k_wout_mfma<<<dim3(32, 16), 256, 0, stream>>>(Amat, DhT, op, WoutT);

    // ---- main: two M-halves; fast DCT replaces cvt+GEMM1 ----
    for (int h = 0; h < 2; ++h) {
        const float* xh = x + (size_t)h * MHALF * IN_F;
        float* outh = (float*)d_out + (size_t)h * MHALF * OUT_F;
        // xa[8192][2048] = orthonormal-DCT(xp)[act] via Makhoul real-FFT
        k_dct<<<MHALF, 256, 0, stream>>>(xh, ipinv, act, tab, xa);
        // GEMM2: out[8192][4096] = xa @ WoutT^T + bias   (32 x 16 = 512 wgs)
        gemm2s<1><<<512, 512, 0, stream>>>(xa, WoutT, (void*)outh, bias,
                                           OUT_F, NACT, OUT_F/256);
    }
}

// Round 21
// 468.542 us; speedup vs baseline: 1.4104x; 1.3131x over previous
//
#include <hip/hip_runtime.h>
#include <cstdint>
#include <cstddef>

typedef __bf16 bf16_t;
typedef float f32x4 __attribute__((ext_vector_type(4)));
typedef __bf16 bf16x8 __attribute__((ext_vector_type(8)));

// ---------------- problem constants ----------------
#define TOKENS      16384
#define IN_F        4096
#define OUT_F       4096
#define NACT        2048
#define MHALF       8192

// ---------------- workspace layout (bytes) ----------------
static constexpr size_t OFF_PERM  = 0;                      // 4096 * 4
static constexpr size_t OFF_ACT   = 16384;                  // 2048 * 4
static constexpr size_t OFF_OIP   = 24576;                  // 4096 * 4
static constexpr size_t OFF_OP    = 40960;                  // 4096 * 4
static constexpr size_t OFF_IPINV = 57344;                  // 4096 * 4
static constexpr size_t OFF_DHT   = 73728;                  // 128*128 * 2 (bf16)
static constexpr size_t OFF_TAB   = 106496;                 // 16384 * 4 cos table
static constexpr size_t OFF_T     = 172032;                 // 8 MB
static constexpr size_t OFF_AM    = OFF_T    + 8388608;     // 32 MB
static constexpr size_t OFF_WOUT  = OFF_AM   + 33554432;    // 16 MB
static constexpr size_t WS_SMALL  = OFF_WOUT + 16777216;    // ~59 MB
// xa-half (32 MB) overlays dead T+Amat region during main phase
static constexpr size_t OFF_XA_S  = OFF_T;

// ---------------- helpers ----------------
__device__ __forceinline__ void gload_lds16(const void* gsrc, void* ldsdst) {
    __builtin_amdgcn_global_load_lds(
        (__attribute__((address_space(1))) void*)(uintptr_t)gsrc,
        (__attribute__((address_space(3))) void*)(uint32_t)(uintptr_t)ldsdst,
        16, 0, 0);
}

__device__ __forceinline__ int is_i64_flag(const int* p) {
    int s = 0;
    #pragma unroll
    for (int i = 1; i < 64; i += 2) s |= p[i];
    return s == 0;
}

// hardware trig, input in REVOLUTIONS (ISA: D = cos/sin(S0 * 2pi)); args in [0,1)
__device__ __forceinline__ float fcos_rev(float rev) {
    float r; asm("v_cos_f32 %0, %1" : "=v"(r) : "v"(rev)); return r;
}
__device__ __forceinline__ float fsin_rev(float rev) {
    float r; asm("v_sin_f32 %0, %1" : "=v"(r) : "v"(rev)); return r;
}

// ---------------- index normalization (int64-or-int32 -> int32) ----------------
__global__ void k_norm_idx(const int* __restrict__ perm_raw,
                           const int* __restrict__ act_raw,
                           const int* __restrict__ oip_raw,
                           int* __restrict__ perm, int* __restrict__ act,
                           int* __restrict__ oip) {
    int i = blockIdx.x * blockDim.x + threadIdx.x;
    int p64 = is_i64_flag(perm_raw);
    int a64 = is_i64_flag(act_raw);
    int o64 = is_i64_flag(oip_raw);
    if (i < 4096) perm[i] = p64 ? perm_raw[2*i] : perm_raw[i];
    if (i < 2048) act[i]  = a64 ? act_raw[2*i]  : act_raw[i];
    if (i < 4096) oip[i]  = o64 ? oip_raw[2*i]  : oip_raw[i];
}

__global__ void k_invert(const int* __restrict__ oip, const int* __restrict__ perm,
                         int* __restrict__ op, int* __restrict__ ipinv) {
    int j = blockIdx.x * 256 + threadIdx.x;
    if (j < 4096) {
        op[oip[j]]     = j;   // forward output perm
        ipinv[perm[j]] = j;   // inverse input perm
    }
}

// ---------------- cos table: tab[i] = cos(pi * i / 8192) (prep kernels only) ----------------
__global__ void k_costab(float* __restrict__ tab) {
    int i = blockIdx.x * 256 + threadIdx.x;    // 64 blocks
    tab[i] = cosf((float)i * 3.834951969e-4f);
}

// ---------------- DCT-128 transpose table, bf16: DhT[m][k] = Dh[k][m] ----------------
__global__ void k_dht(const float* __restrict__ tab, bf16_t* __restrict__ DhT) {
    int idx = blockIdx.x * 256 + threadIdx.x;   // 64 blocks
    int m = idx >> 7, k = idx & 127;
    unsigned ph = ((unsigned)(2*m + 1) * (unsigned)k) & 511u;   // period 4n = 512
    float v = 0.125f * tab[ph << 5];                            // cos(pi*ph/256)
    if (k == 0) v *= 0.70710678119f;
    DhT[m*128 + k] = (bf16_t)v;
}

// ---------------- T[r,j,q,k,u] = sum_s G2[r,j,q,s] * G3[s,k,u] ----------------
__global__ __launch_bounds__(256) void k_build_T(const float* __restrict__ G2,
                                                 const float* __restrict__ G3,
                                                 float* __restrict__ T) {
    __shared__ alignas(16) float g3s[64*8*16];   // 32 KB
    __shared__ float g2t[64*16];                 // [s][q], 4 KB
    int rj = blockIdx.x;                          // 1024 blocks: r*16 + j
    int r = rj >> 4, j = rj & 15;
    for (int idx = threadIdx.x; idx < 8192; idx += 256) g3s[idx] = G3[idx];
    for (int idx = threadIdx.x; idx < 1024; idx += 256) {
        int s = idx >> 4, q = idx & 15;
        g2t[idx] = G2[((size_t)((r*16 + j)*16 + q))*64 + s];
    }
    __syncthreads();
    int q = threadIdx.x >> 4, u = threadIdx.x & 15;
    float acc[8] = {0.f};
    for (int s = 0; s < 64; ++s) {
        float g2 = g2t[s*16 + q];
        #pragma unroll
        for (int k = 0; k < 8; ++k) acc[k] += g2 * g3s[(s*8 + k)*16 + u];
    }
    size_t base = ((size_t)((r*16 + j)*16 + q) * 8) * 16 + u;
    #pragma unroll
    for (int k = 0; k < 8; ++k) T[base + k*16] = acc[k];
}

// ---------------- A[cin][cout] = sum_r G1[i,p,r] * T[r,j,q,k,u] ----------------
__global__ __launch_bounds__(256) void k_build_A(const float* __restrict__ G1,
                                                 const float* __restrict__ T,
                                                 float* __restrict__ Amat) {
    __shared__ alignas(16) float Tl[64*16*16];   // [r][q][slot-swizzled], 64 KB
    __shared__ float g1t[64*16];                 // [r][p], 4 KB
    int cin = blockIdx.x;                         // 2048 blocks
    int i = cin >> 7, j = (cin >> 3) & 15, k = cin & 7;
    #pragma unroll
    for (int it = 0; it < 16; ++it) {
        int idx = it*256 + threadIdx.x;          // f32x4 index, 0..4095
        int slot = idx & 3, q = (idx >> 2) & 15, r = idx >> 6;
        f32x4 tv = *(const f32x4*)&T[(((((size_t)r*16 + j)*16 + q)*8) + k)*16 + slot*4];
        *(f32x4*)&Tl[(r*16 + q)*16 + ((slot ^ ((q >> 1) & 3)) << 2)] = tv;
    }
    for (int idx = threadIdx.x; idx < 1024; idx += 256) {
        int r = idx >> 4, p = idx & 15;
        g1t[idx] = G1[(i*16 + p)*64 + r];
    }
    __syncthreads();
    int p = threadIdx.x >> 4, q = threadIdx.x & 15;
    int qs = (q >> 1) & 3;
    f32x4 acc4[4];
    #pragma unroll
    for (int a = 0; a < 4; ++a) acc4[a] = (f32x4){0.f, 0.f, 0.f, 0.f};
    for (int r = 0; r < 64; ++r) {
        float g = g1t[r*16 + p];
        #pragma unroll
        for (int ub = 0; ub < 4; ++ub) {         // static acc index, runtime address
            f32x4 tv = *(const f32x4*)&Tl[(r*16 + q)*16 + ((ub ^ qs) << 2)];
            acc4[ub] += tv * g;
        }
    }
    size_t base = (size_t)cin * 4096 + p*256 + q*16;
    #pragma unroll
    for (int ub = 0; ub < 4; ++ub) *(f32x4*)&Amat[base + ub*4] = acc4[ub];
}

// ---- WoutT via MFMA: Out[128c][128m] = A_blk[c][k](bf16) x DhT[m][k](bf16)^T ----
__global__ __launch_bounds__(256) void k_wout_mfma(const float* __restrict__ Amat,
                                                   const bf16_t* __restrict__ DhT,
                                                   const int* __restrict__ op,
                                                   bf16_t* __restrict__ WoutT) {
    __shared__ alignas(16) bf16_t Al[128*128];   // 32 KB  [c][k]
    __shared__ alignas(16) bf16_t Bl[128*128];   // 32 KB  [m][k]
    const int h  = blockIdx.x;
    const int c0 = blockIdx.y * 128;
    const int t = threadIdx.x, lane = t & 63, wv = t >> 6;
    const int wm = wv >> 1, wn = wv & 1;
    const int frow = lane & 15, kg = lane >> 4;

    #pragma unroll
    for (int it = 0; it < 8; ++it) {
        int idx = it*256 + t;                    // 0..2047
        int row = idx >> 4, slot = idx & 15;
        int dst = row*256 + ((slot*16) ^ ((row & 7) << 4));   // byte offset
        const float* s = Amat + (size_t)(c0 + row)*4096 + h*128 + slot*8;
        f32x4 v0 = *(const f32x4*)s;
        f32x4 v1 = *(const f32x4*)(s + 4);
        bf16x8 av;
        av[0]=(bf16_t)v0[0]; av[1]=(bf16_t)v0[1]; av[2]=(bf16_t)v0[2]; av[3]=(bf16_t)v0[3];
        av[4]=(bf16_t)v1[0]; av[5]=(bf16_t)v1[1]; av[6]=(bf16_t)v1[2]; av[7]=(bf16_t)v1[3];
        *(bf16x8*)((char*)Al + dst) = av;
        bf16x8 dv = *(const bf16x8*)(DhT + row*128 + slot*8);
        *(bf16x8*)((char*)Bl + dst) = dv;
    }
    __syncthreads();

    f32x4 acc[4][4];
    #pragma unroll
    for (int a = 0; a < 4; ++a)
        #pragma unroll
        for (int b = 0; b < 4; ++b) acc[a][b] = (f32x4){0.f, 0.f, 0.f, 0.f};

    #pragma unroll
    for (int ks = 0; ks < 4; ++ks) {
        bf16x8 af[4], bfr[4];
        #pragma unroll
        for (int mt = 0; mt < 4; ++mt) {
            int r = wm*64 + mt*16 + frow;
            af[mt] = *(const bf16x8*)((char*)Al + r*256 + ((ks*64 + kg*16) ^ ((r & 7) << 4)));
        }
        #pragma unroll
        for (int nt = 0; nt < 4; ++nt) {
            int r = wn*64 + nt*16 + frow;
            bfr[nt] = *(const bf16x8*)((char*)Bl + r*256 + ((ks*64 + kg*16) ^ ((r & 7) << 4)));
        }
        #pragma unroll
        for (int mt = 0; mt < 4; ++mt)
            #pragma unroll
            for (int nt = 0; nt < 4; ++nt)
                acc[mt][nt] = __builtin_amdgcn_mfma_f32_16x16x32_bf16(
                    af[mt], bfr[nt], acc[mt][nt], 0, 0, 0);
    }

    const int ccol  = lane & 15;
    const int crow0 = (lane >> 4) * 4;
    #pragma unroll
    for (int nt = 0; nt < 4; ++nt) {
        const int m = wn*64 + nt*16 + ccol;
        const int jj = op[h*128 + m];
        #pragma unroll
        for (int mt = 0; mt < 4; ++mt) {
            #pragma unroll
            for (int i = 0; i < 4; ++i) {
                const int c = c0 + wm*64 + mt*16 + crow0 + i;
                WoutT[(size_t)jj * 2048 + c] = (bf16_t)acc[mt][nt][i];
            }
        }
    }
}

// ======== fast DCT-4096 (Makhoul real-FFT) + input perm + freq select ========
// r19/r20-validated fused double-stage network, complex float2 LDS layout.
// Twiddles now computed with v_cos_f32/v_sin_f32 (revolutions; all args exact
// multiples of 1/16384, in [0,1)) -- eliminates the divergent tab[] gathers
// (up to 64 cachelines/wave-instr) identified as the r20 residual bottleneck.
#define PADF(i) ((i) + ((i) >> 4))
#define REV16K  6.103515625e-5f   // 1/16384
__global__ __launch_bounds__(256) void k_dct(const float* __restrict__ x,
                                             const int* __restrict__ ipinv,
                                             const int* __restrict__ act,
                                             bf16_t* __restrict__ xa) {
    __shared__ float2 cz[2176];    // 2048 complex + pad, 17.4 KB
    const int tid = threadIdx.x;
    const float* xr = x + (size_t)blockIdx.x * 4096;

    // scatter: load coalesced, place at Makhoul/perm position (.x=re, .y=im)
    auto scat = [&](int m, float val) {
        int p = (m & 1) ? (4095 - (m >> 1)) : (m >> 1);
        if (p & 1) cz[PADF(p >> 1)].y = val; else cz[PADF(p >> 1)].x = val;
    };
    #pragma unroll
    for (int b = 0; b < 4; ++b) {
        int r0 = (b*256 + tid) * 4;
        f32x4 xv = *(const f32x4*)(xr + r0);
        int4  mv = *(const int4*)(ipinv + r0);
        scat(mv.x, xv[0]); scat(mv.y, xv[1]); scat(mv.z, xv[2]); scat(mv.w, xv[3]);
    }
    __syncthreads();

    // 5 fused double-stages: s = 0,2,4,6,8 (sh = 10-s >= 2)
    #pragma unroll
    for (int ds = 0; ds < 5; ++ds) {
        const int s  = 2*ds;
        const int sh = 10 - s;
        #pragma unroll
        for (int b = 0; b < 2; ++b) {
            int q  = b*256 + tid;                    // group id 0..511
            int j  = q & ((1 << (sh-1)) - 1);
            int g  = q >> (sh - 1);
            int i0 = (g << (sh + 1)) + j;
            int p0 = PADF(i0);
            int p1 = PADF(i0 + (1 << (sh-1)));
            int p2 = PADF(i0 + (1 << sh));
            int p3 = PADF(i0 + (1 << sh) + (1 << (sh-1)));
            int ua = j << (3 + s);                   // < 8192
            float ra = (float)ua * REV16K;           // [0, 0.5)
            float ca = fcos_rev(ra), sa = fsin_rev(ra);
            float rc = (float)(ua << 1) * REV16K;    // [0, 1)
            float cc = fcos_rev(rc), sc = fsin_rev(rc);
            float2 v0 = cz[p0], v1 = cz[p1], v2 = cz[p2], v3 = cz[p3];
            // stage s: pairs (0,2) with W(ua), (1,3) with W(ua+4096)=(-sa,ca)
            float t0r=v0.x+v2.x, t0m=v0.y+v2.y;
            float dr=v0.x-v2.x,  dm=v0.y-v2.y;
            float t2r=dr*ca+dm*sa, t2m=dm*ca-dr*sa;
            float t1r=v1.x+v3.x, t1m=v1.y+v3.y;
            float er=v1.x-v3.x,  em=v1.y-v3.y;
            float t3r=em*ca-er*sa, t3m=-em*sa-er*ca;
            // stage s+1: pairs (0,1) and (2,3), both with W(2*ua)
            float fr=t0r-t1r, fm=t0m-t1m;
            float gr=t2r-t3r, gm=t2m-t3m;
            cz[p0] = make_float2(t0r+t1r, t0m+t1m);
            cz[p1] = make_float2(fr*cc+fm*sc, fm*cc-fr*sc);
            cz[p2] = make_float2(t2r+t3r, t2m+t3m);
            cz[p3] = make_float2(gr*cc+gm*sc, gm*cc-gr*sc);
        }
        __syncthreads();
    }
    // final stage s=10 (h=1, twiddle-free)
    #pragma unroll
    for (int b = 0; b < 4; ++b) {
        int q = b*256 + tid;
        int p0 = PADF(2*q), p1 = PADF(2*q + 1);
        float2 a = cz[p0], bb = cz[p1];
        cz[p0] = make_float2(a.x + bb.x, a.y + bb.y);
        cz[p1] = make_float2(a.x - bb.x, a.y - bb.y);
    }
    __syncthreads();

    // unpack + DCT twiddle + select + scale + store (coalesced in c)
    #pragma unroll
    for (int b = 0; b < 8; ++b) {
        int c = b*256 + tid;
        int k = act[c];
        int t, cj;
        if (k <= 2048) { t = k; cj = 0; } else { t = 4096 - k; cj = 1; }
        int k1 = t & 2047, km = (2048 - k1) & 2047;
        int p1 = PADF((int)(__brev((unsigned)k1) >> 21));
        int pm = PADF((int)(__brev((unsigned)km) >> 21));
        float2 z1 = cz[p1], zm = cz[pm];
        float ar = z1.x, ai = z1.y;
        float br = zm.x, bi = zm.y;
        float sr = ar + br, si = ai - bi;
        float dr = ar - br, di = ai + bi;
        float ru = (float)((4 * t) & 16383) * REV16K;
        float cw = fcos_rev(ru), sw = fsin_rev(ru);
        float vr = 0.5f * (sr - sw * dr + cw * di);
        float vi = 0.5f * (si - cw * dr - sw * di);
        if (cj) vi = -vi;
        float rk = (float)k * REV16K;                // [0, 0.25)
        float ck = fcos_rev(rk), sk = fsin_rev(rk);
        float X = ck * vr + sk * vi;
        float sc = (k == 0) ? 0.015625f : 0.02209708691f;   // sqrt(2/4096), k0 * 1/sqrt2
        xa[(size_t)blockIdx.x * 2048 + c] = (bf16_t)(X * sc);
    }
}

// ---------------- shared GEMM helpers ----------------
__device__ __forceinline__ bf16x8 read_frag(const bf16_t* lds, int row, int slot) {
    return *(const bf16x8*)(lds + (((row << 3) + (slot ^ (row & 7))) << 3));
}

// ====== 256x256 8-wave GEMM, BK=64, single barrier/iter (measured 4310 cy/tile) ======
// NOTE (r12 lesson): do NOT raise min-waves-per-EU -- acc[8][4] needs 128 VGPR.
template<int OUTF>   // 0 -> bf16 out, 1 -> f32 out + bias
__global__ __launch_bounds__(512, 2)
void gemm2s(const bf16_t* __restrict__ A, const bf16_t* __restrict__ Bt,
            void* __restrict__ Cp, const float* __restrict__ bias,
            int N, int K, int nbn) {
    __shared__ alignas(16) bf16_t lds[2][2][256*64];   // 128 KB

    const int tid  = threadIdx.x;
    const int lane = tid & 63;
    const int wid  = tid >> 6;
    const int wm   = wid >> 2;
    const int wn   = wid & 3;
    const int frow = lane & 15;
    const int kg   = lane >> 4;

    const int nwg = gridDim.x;
    const int cpx = nwg >> 3;
    const int swz = (blockIdx.x & 7) * cpx + (blockIdx.x >> 3);
    const int m0  = (swz / nbn) * 256;
    const int n0  = (swz % nbn) * 256;

    const bf16_t* gA = A  + (size_t)m0 * K;
    const bf16_t* gB = Bt + (size_t)n0 * K;

    auto stage = [&](int kt) {
        bf16_t* dA = &lds[kt & 1][0][0];
        bf16_t* dB = &lds[kt & 1][1][0];
        #pragma unroll
        for (int i = 0; i < 4; ++i) {
            int q = i*512 + tid, row = q >> 3, s = q & 7;
            gload_lds16(gA + (size_t)row*K + kt*64 + ((s ^ (row & 7)) << 3), dA + q*8);
        }
        #pragma unroll
        for (int i = 0; i < 4; ++i) {
            int q = i*512 + tid, row = q >> 3, s = q & 7;
            gload_lds16(gB + (size_t)row*K + kt*64 + ((s ^ (row & 7)) << 3), dB + q*8);
        }
    };

    f32x4 acc[8][4];
    #pragma unroll
    for (int a = 0; a < 8; ++a)
        #pragma unroll
        for (int b = 0; b < 4; ++b) acc[a][b] = (f32x4){0.f, 0.f, 0.f, 0.f};

    const int NT = K >> 6;
    stage(0);
    asm volatile("s_waitcnt vmcnt(0)" ::: "memory");
    __builtin_amdgcn_s_barrier();

    for (int t = 0; t < NT; ++t) {
        const int cur = t & 1;
        if (t + 1 < NT) stage(t + 1);

        const bf16_t* lA = &lds[cur][0][0];
        const bf16_t* lB = &lds[cur][1][0];
        __builtin_amdgcn_s_setprio(1);
        #pragma unroll
        for (int ks = 0; ks < 2; ++ks) {
            bf16x8 bfr[4];
            #pragma unroll
            for (int nt = 0; nt < 4; ++nt)
                bfr[nt] = read_frag(lB, wn*64 + nt*16 + frow, ks*4 + kg);
            #pragma unroll
            for (int mt = 0; mt < 8; ++mt) {
                bf16x8 af = read_frag(lA, wm*128 + mt*16 + frow, ks*4 + kg);
                #pragma unroll
                for (int nt = 0; nt < 4; ++nt)
                    acc[mt][nt] = __builtin_amdgcn_mfma_f32_16x16x32_bf16(
                        af, bfr[nt], acc[mt][nt], 0, 0, 0);
            }
        }
        __builtin_amdgcn_s_setprio(0);

        if (t + 1 < NT) {
            asm volatile("s_waitcnt vmcnt(0)" ::: "memory");   // free: issued pre-compute
            __builtin_amdgcn_s_barrier();                      // publish + WAR fence
        }
    }

    const int ccol  = lane & 15;
    const int crow0 = (lane >> 4) * 4;
    #pragma unroll
    for (int nt = 0; nt < 4; ++nt) {
        const int col = n0 + wn*64 + nt*16 + ccol;
        float bv = 0.f;
        if constexpr (OUTF == 1) bv = bias[col];
        #pragma unroll
        for (int mt = 0; mt < 8; ++mt) {
            const int row = m0 + wm*128 + mt*16 + crow0;
            #pragma unroll
            for (int i = 0; i < 4; ++i) {
                if constexpr (OUTF == 1)
                    ((float*)Cp)[(size_t)(row + i)*N + col] = acc[mt][nt][i] + bv;
                else
                    ((bf16_t*)Cp)[(size_t)(row + i)*N + col] = (bf16_t)acc[mt][nt][i];
            }
        }
    }
}

// ---------------- launcher ----------------
extern "C" void kernel_launch(void* const* d_in, const int* in_sizes, int n_in,
                              void* d_out, int out_size, void* d_ws, size_t ws_size,
                              hipStream_t stream) {
    (void)in_sizes; (void)n_in; (void)out_size;
    const float* x    = (const float*)d_in[0];
    const float* G1   = (const float*)d_in[1];
    const float* G2   = (const float*)d_in[2];
    const float* G3   = (const float*)d_in[3];
    const float* bias = (const float*)d_in[4];
    const int* perm_raw = (const int*)d_in[5];
    const int* act_raw  = (const int*)d_in[6];
    const int* oip_raw  = (const int*)d_in[7];

    if (ws_size < WS_SMALL) return;

    char* ws = (char*)d_ws;
    int*    perm  = (int*)   (ws + OFF_PERM);
    int*    act   = (int*)   (ws + OFF_ACT);
    int*    oip   = (int*)   (ws + OFF_OIP);
    int*    op    = (int*)   (ws + OFF_OP);
    int*    ipinv = (int*)   (ws + OFF_IPINV);
    bf16_t* DhT   = (bf16_t*)(ws + OFF_DHT);
    float*  tab   = (float*) (ws + OFF_TAB);
    float*  T     = (float*) (ws + OFF_T);
    float*  Amat  = (float*) (ws + OFF_AM);
    bf16_t* WoutT = (bf16_t*)(ws + OFF_WOUT);
    bf16_t* xa    = (bf16_t*)(ws + OFF_XA_S);   // overlays dead T/Amat during main

    // ---- prep (weights) ----
    k_norm_idx<<<16, 256, 0, stream>>>(perm_raw, act_raw, oip_raw, perm, act, oip);
    k_invert  <<<16, 256, 0, stream>>>(oip, perm, op, ipinv);
    k_costab  <<<64, 256, 0, stream>>>(tab);
    k_dht     <<<64, 256, 0, stream>>>(tab, DhT);
    k_build_T <<<1024, 256, 0, stream>>>(G2, G3, T);
    k_build_A <<<2048, 256, 0, stream>>>(G1, T, Amat);
    k_wout_mfma<<<dim3(32, 16), 256, 0, stream>>>(Amat, DhT, op, WoutT);

    // ---- main: two M-halves; fast DCT replaces cvt+GEMM1 ----
    for (int h = 0; h < 2; ++h) {
        const float* xh = x + (size_t)h * MHALF * IN_F;
        float* outh = (float*)d_out + (size_t)h * MHALF * OUT_F;
        // xa[8192][2048] = orthonormal-DCT(xp)[act] via Makhoul real-FFT
        k_dct<<<MHALF, 256, 0, stream>>>(xh, ipinv, act, xa);
        // GEMM2: out[8192][4096] = xa @ WoutT^T + bias   (32 x 16 = 512 wgs)
        gemm2s<1><<<512, 512, 0, stream>>>(xa, WoutT, (void*)outh, bias,
                                           OUT_F, NACT, OUT_F/256);
    }
}